// Round 17
// baseline (131.964 us; speedup 1.0000x reference)
//
#include <hip/hip_runtime.h>
#include <math.h>

typedef unsigned short u16;
typedef unsigned int u32;
typedef __attribute__((ext_vector_type(8))) short short8;
typedef __attribute__((ext_vector_type(8))) u16 u16x8;
typedef __attribute__((ext_vector_type(4))) float f32x4;

#define SW(i) ((i) ^ (((i) >> 4) & 15))

#if __has_builtin(__builtin_amdgcn_rcpf)
#define RCP(x) __builtin_amdgcn_rcpf(x)
#else
#define RCP(x) (1.0f / (x))
#endif

#define LBAR()                                                                 \
  do {                                                                         \
    asm volatile("s_waitcnt lgkmcnt(0)" ::: "memory");                         \
    __builtin_amdgcn_s_barrier();                                              \
    __builtin_amdgcn_sched_barrier(0);                                         \
  } while (0)

static __device__ __forceinline__ u16 f2bf(float x) {
  unsigned u = __builtin_bit_cast(unsigned, x);
  return (u16)((u + 0x7FFFu + ((u >> 16) & 1u)) >> 16);
}

static __device__ __forceinline__ float2 cmul(float2 a, float2 b) {
  return make_float2(a.x * b.x - a.y * b.y, a.x * b.y + a.y * b.x);
}
static __device__ __forceinline__ float2 cadd(float2 a, float2 b) {
  return make_float2(a.x + b.x, a.y + b.y);
}
static __device__ __forceinline__ float2 conjf2(float2 a) {
  return make_float2(a.x, -a.y);
}
static __device__ __forceinline__ float2 mkC(float a, float b) {
  return make_float2(a, b);
}
static __device__ __forceinline__ float4 pk2(float2 p, float2 q) {
  return make_float4(p.x, p.y, q.x, q.y);
}

static __device__ __forceinline__ float2 twd(int j) {
  float s, c;
  __sincosf((float)j * -0.00613592315154256492f, &s, &c);
  return make_float2(c, s);
}

static __device__ __forceinline__ float gelu_fast(float y) {
  const float t = __builtin_fmaf(0.044715f * y * y, y, y);
  const float e = __expf(-1.5957691216f * t);
  return y * RCP(1.f + e);
}

static __device__ __forceinline__ u32 pack_out(float2 r) {
  const u32 lo = f2bf(gelu_fast(r.x));
  const u32 hi = f2bf(gelu_fast(-r.y));
  return lo | (hi << 16);
}

static __device__ __forceinline__ void gload_lds16(const void* g, void* l) {
  __builtin_amdgcn_global_load_lds(
      (const __attribute__((address_space(1))) u32*)g,
      (__attribute__((address_space(3))) u32*)l, 16, 0, 0);
}

#define BF4(A, B, C, D, Y0, Y1, Y2, Y3)                                        \
  {                                                                            \
    const float apcr = (A).x + (C).x, apci = (A).y + (C).y;                    \
    const float amcr = (A).x - (C).x, amci = (A).y - (C).y;                    \
    const float bpdr = (B).x + (D).x, bpdi = (B).y + (D).y;                    \
    const float bmdr = (B).x - (D).x, bmdi = (B).y - (D).y;                    \
    Y0 = make_float2(apcr + bpdr, apci + bpdi);                                \
    Y2 = make_float2(apcr - bpdr, apci - bpdi);                                \
    Y1 = make_float2(amcr + bmdi, amci - bmdr);                                \
    Y3 = make_float2(amcr - bmdi, amci + bmdr);                                \
  }

// ---------------- K1: merged hope-kernel + filter coeffs (+D folded) + W->bf16
static __device__ __forceinline__ void hope_sum(
    const float* __restrict__ log_dt, const float* __restrict__ Hr,
    const float* __restrict__ Hi, int h, int l, float* outr, float* outi) {
  const float dt = expf(log_dt[h]);
  const float phi = 6.28318530717958647692f * (float)l * (1.0f / 1024.0f);
  float sphi, cphi;
  sincosf(phi, &sphi, &cphi);
  const float nr = (1.f + dt) * cphi + dt - 1.f;
  const float ni = (1.f + dt) * sphi;
  const float dr = (dt - 1.f) * cphi + dt + 1.f;
  const float di = (dt - 1.f) * sphi;
  const float theta = atan2f(ni * dr - nr * di, nr * dr + ni * di);
  float sw, cw;
  sincosf(theta, &sw, &cw);
  const float wr = cw, wi = -sw;  // e^{-i theta}
  float cr = wr, ci = wi;
  float ar = 0.f, ai = 0.f;
  const float* __restrict__ hr = Hr + h * 64;
  const float* __restrict__ hi = Hi + h * 64;
  for (int n = 0; n < 64; ++n) {
    const float a = hr[n], bb = hi[n];
    ar += a * cr - bb * ci;
    ai += a * ci + bb * cr;
    const float t = cr * wr - ci * wi;
    ci = cr * wi + ci * wr;
    cr = t;
  }
  *outr = ar;
  *outi = ai;
}

__global__ __launch_bounds__(512) void build_kep(
    const float* __restrict__ log_dt, const float* __restrict__ Hr,
    const float* __restrict__ Hi, const float* __restrict__ Dv,
    const float* __restrict__ W, float2* __restrict__ kep,
    u16* __restrict__ Wb) {
  __shared__ float2 K1[1024], K2[1024];
  const int c = blockIdx.x;
  const int t = threadIdx.x;
  Wb[c * 1024 + t] = f2bf(W[c * 1024 + t]);
  Wb[c * 1024 + 512 + t] = f2bf(W[c * 1024 + 512 + t]);
  float r, i;
  hope_sum(log_dt, Hr, Hi, c, t, &r, &i);             K1[t] = make_float2(r, i);
  hope_sum(log_dt, Hr, Hi, c, t + 512, &r, &i);       K1[t + 512] = make_float2(r, i);
  hope_sum(log_dt, Hr, Hi, c + 512, t, &r, &i);       K2[t] = make_float2(r, i);
  hope_sum(log_dt, Hr, Hi, c + 512, t + 512, &r, &i); K2[t + 512] = make_float2(r, i);
  __syncthreads();
  const float s = 1.0f / 2048.0f;
  const float dcs = Dv[c] * s;
  for (int q = t; q <= 512; q += 512) {
    float2 kf, kg;
    {
      const int qa = q;
      kf = (qa == 0) ? make_float2(K1[0].x * s, 0.f)
                     : make_float2(0.5f * s * (K1[qa].x + K2[qa - 1].x),
                                   0.5f * s * (K1[qa].y - K2[qa - 1].y));
      const int qb = 1024 - q;
      kg = (qb == 1024) ? make_float2(K2[1023].x * s, 0.f)
           : (qb == 0)  ? make_float2(K1[0].x * s, 0.f)
                        : make_float2(0.5f * s * (K1[qb].x + K2[qb - 1].x),
                                      0.5f * s * (K1[qb].y - K2[qb - 1].y));
    }
    kf.x += dcs;
    kg.x += dcs;
    float2 C1, C2, C3, C4;
    if (q == 0) {
      C1 = make_float2(kf.x + kg.x, kg.y - kf.y);
      C2 = make_float2(-(kg.y + kf.y), kg.x - kf.x);
      C3 = C2;
      C4 = C1;
    } else {
      float st, ct;
      sincosf(3.14159265358979323846f * (float)q * (1.f / 1024.f), &st, &ct);
      const float2 A1 = make_float2(1.f - st, -ct);
      const float2 A2 = make_float2(1.f + st, ct);
      const float2 kgc = make_float2(kg.x, -kg.y);
      const float2 t1 = cmul(kf, A1), t2 = cmul(kgc, A2);
      const float2 t3 = cmul(kf, A2), t4 = cmul(kgc, A1);
      const float2 p1 = make_float2(0.5f * (t1.x + t2.x), 0.5f * (t1.y + t2.y));
      const float2 p2 = make_float2(0.5f * (t3.x + t4.x), 0.5f * (t3.y + t4.y));
      const float2 q1 = make_float2(0.5f * (t1.x - t2.x), 0.5f * (t1.y - t2.y));
      const float2 q2 = make_float2(0.5f * (t3.x - t4.x), 0.5f * (t3.y - t4.y));
      const float2 iWc = make_float2(-st, ct);
      const float2 r1 = cmul(iWc, q1), r2 = cmul(iWc, q2);
      C1 = make_float2(p1.x + r1.x, -(p1.y + r1.y));
      C2 = make_float2(p2.x + r2.x, -(p2.y + r2.y));
      C3 = make_float2(p1.x - r1.x, p1.y - r1.y);
      C4 = make_float2(p2.x - r2.x, p2.y - r2.y);
    }
    float2* o = kep + ((size_t)c * 513 + q) * 4;
    o[0] = C1; o[1] = C2; o[2] = C3; o[3] = C4;
  }
}

// ------- K2: Stockham rfft-conv (R16 structure, unchanged) --------------------
static __device__ __forceinline__ void stage_pair(
    const float4* __restrict__ S, float4* __restrict__ D, int t, int sh) {
  const int m = 1 << sh;
  const int kk = t & (m - 1);
  const int o = kk + ((t >> sh) << (sh + 2));
  const float4 va = S[SW(t)];
  const float4 vb = S[SW(t + 256)];
  const float4 vc = S[SW(t + 512)];
  const float4 vd = S[SW(t + 768)];
  const float2 a0 = mkC(va.x, va.y), a1 = mkC(va.z, va.w);
  const float2 b0 = mkC(vb.x, vb.y), b1 = mkC(vb.z, vb.w);
  const float2 c0 = mkC(vc.x, vc.y), c1 = mkC(vc.z, vc.w);
  const float2 d0 = mkC(vd.x, vd.y), d1 = mkC(vd.z, vd.w);
  float2 x0, x1, x2, x3, z0, z1, z2, z3;
  BF4(a0, b0, c0, d0, x0, x1, x2, x3);
  BF4(a1, b1, c1, d1, z0, z1, z2, z3);
  const float2 w1 = twd((t >> sh) << sh);
  const float2 w2 = cmul(w1, w1);
  const float2 w3 = cmul(w2, w1);
  D[SW(o)] = pk2(x0, z0);
  D[SW(o + m)] = pk2(cmul(w1, x1), cmul(w1, z1));
  D[SW(o + 2 * m)] = pk2(cmul(w2, x2), cmul(w2, z2));
  D[SW(o + 3 * m)] = pk2(cmul(w3, x3), cmul(w3, z3));
}

static __device__ __forceinline__ void stage_pair_last(
    const float4* __restrict__ S, float4* __restrict__ D, int t) {
  const float4 va = S[SW(t)];
  const float4 vb = S[SW(t + 256)];
  const float4 vc = S[SW(t + 512)];
  const float4 vd = S[SW(t + 768)];
  const float2 a0 = mkC(va.x, va.y), a1 = mkC(va.z, va.w);
  const float2 b0 = mkC(vb.x, vb.y), b1 = mkC(vb.z, vb.w);
  const float2 c0 = mkC(vc.x, vc.y), c1 = mkC(vc.z, vc.w);
  const float2 d0 = mkC(vd.x, vd.y), d1 = mkC(vd.z, vd.w);
  float2 x0, x1, x2, x3, z0, z1, z2, z3;
  BF4(a0, b0, c0, d0, x0, x1, x2, x3);
  BF4(a1, b1, c1, d1, z0, z1, z2, z3);
  D[SW(t)] = pk2(x0, z0);
  D[SW(t + 256)] = pk2(x1, z1);
  D[SW(t + 512)] = pk2(x2, z2);
  D[SW(t + 768)] = pk2(x3, z3);
}

__global__ __launch_bounds__(256) void fft_conv(
    const float* __restrict__ u, const float2* __restrict__ kep,
    u16* __restrict__ y) {
  __shared__ float4 bufA[1024], bufB[1024];  // 32768 B
  const int bq = blockIdx.x, c = blockIdx.y;
  const int t = threadIdx.x;

  const float4* __restrict__ krow4 = (const float4*)(kep + (size_t)c * (513 * 4));
  const float4 cA0 = krow4[2 * t];
  const float4 cA1 = krow4[2 * (t + 256)];
  const float4 cC  = krow4[2 * (512 - t) + 1];
  const float4 cDq = krow4[2 * (256 - t) + 1];
  const float4 cM  = krow4[1024];

  const int b0 = bq * 2, b1 = bq * 2 + 1;
  const float2* __restrict__ u20 = (const float2*)(u + ((size_t)(b0 * 512 + c)) * 2048);
  const float2* __restrict__ u21 = (const float2*)(u + ((size_t)(b1 * 512 + c)) * 2048);
  u32* __restrict__ yr0 = (u32*)(y + ((size_t)(b0 * 512 + c)) * 2048);
  u32* __restrict__ yr1 = (u32*)(y + ((size_t)(b1 * 512 + c)) * 2048);
  float4* A = bufA;
  float4* B = bufB;

  {
    float2 v0[4], v1[4];
    #pragma unroll
    for (int q = 0; q < 4; ++q) {
      v0[q] = u20[t + 256 * q];
      v1[q] = u21[t + 256 * q];
    }
    float2 x0, x1, x2, x3, z0, z1, z2, z3;
    BF4(v0[0], v0[1], v0[2], v0[3], x0, x1, x2, x3);
    BF4(v1[0], v1[1], v1[2], v1[3], z0, z1, z2, z3);
    const float2 w1 = twd(t);
    const float2 w2 = cmul(w1, w1);
    const float2 w3 = cmul(w2, w1);
    const int o = 4 * t;
    A[SW(o)] = pk2(x0, z0);
    A[SW(o + 1)] = pk2(cmul(w1, x1), cmul(w1, z1));
    A[SW(o + 2)] = pk2(cmul(w2, x2), cmul(w2, z2));
    A[SW(o + 3)] = pk2(cmul(w3, x3), cmul(w3, z3));
  }
  LBAR();
  stage_pair(A, B, t, 2); LBAR();
  stage_pair(B, A, t, 4); LBAR();
  stage_pair(A, B, t, 6); LBAR();
  stage_pair_last(B, A, t); LBAR();

  {
    const int gp0 = (1024 - t) & 1023;
    const float2 w1 = twd(t);
    const float2 w2 = cmul(w1, w1);
    const float2 w3 = cmul(w2, w1);
    const int o = 4 * t;
    const float4 Vf0 = A[SW(t)],       Vg0 = A[SW(gp0)];
    const float4 Vf1 = A[SW(t + 256)], Vg1 = A[SW(768 - t)];
    const float4 Vc  = A[SW(t + 512)], Vcf = A[SW(512 - t)];
    const float4 Vd  = A[SW(t + 768)], Vdf = A[SW(256 - t)];
    const float2 CA1 = mkC(cA0.x, cA0.y), CA2 = mkC(cA0.z, cA0.w);
    const float2 CB1 = mkC(cA1.x, cA1.y), CB2 = mkC(cA1.z, cA1.w);
    const float2 CC3 = mkC(cC.x, cC.y),   CC4 = mkC(cC.z, cC.w);
    const float2 CD3 = mkC(cDq.x, cDq.y), CD4 = mkC(cDq.z, cDq.w);
    const float2 CM1 = mkC(cM.x, cM.y),   CM2 = mkC(cM.z, cM.w);
    float2 Da0, Da1, Db0, Db1, Dc0, Dc1, Dd0, Dd1;
    Da0 = cadd(cmul(CA1, conjf2(mkC(Vf0.x, Vf0.y))), cmul(CA2, mkC(Vg0.x, Vg0.y)));
    Da1 = cadd(cmul(CA1, conjf2(mkC(Vf0.z, Vf0.w))), cmul(CA2, mkC(Vg0.z, Vg0.w)));
    Db0 = cadd(cmul(CB1, conjf2(mkC(Vf1.x, Vf1.y))), cmul(CB2, mkC(Vg1.x, Vg1.y)));
    Db1 = cadd(cmul(CB1, conjf2(mkC(Vf1.z, Vf1.w))), cmul(CB2, mkC(Vg1.z, Vg1.w)));
    if (t == 0) {
      Dc0 = cadd(cmul(CM1, conjf2(mkC(Vc.x, Vc.y))), cmul(CM2, mkC(Vc.x, Vc.y)));
      Dc1 = cadd(cmul(CM1, conjf2(mkC(Vc.z, Vc.w))), cmul(CM2, mkC(Vc.z, Vc.w)));
    } else {
      Dc0 = cadd(cmul(CC3, mkC(Vcf.x, Vcf.y)), cmul(CC4, conjf2(mkC(Vc.x, Vc.y))));
      Dc1 = cadd(cmul(CC3, mkC(Vcf.z, Vcf.w)), cmul(CC4, conjf2(mkC(Vc.z, Vc.w))));
    }
    Dd0 = cadd(cmul(CD3, mkC(Vdf.x, Vdf.y)), cmul(CD4, conjf2(mkC(Vd.x, Vd.y))));
    Dd1 = cadd(cmul(CD3, mkC(Vdf.z, Vdf.w)), cmul(CD4, conjf2(mkC(Vd.z, Vd.w))));
    float2 x0, x1, x2, x3, z0, z1, z2, z3;
    BF4(Da0, Db0, Dc0, Dd0, x0, x1, x2, x3);
    BF4(Da1, Db1, Dc1, Dd1, z0, z1, z2, z3);
    B[SW(o)] = pk2(x0, z0);
    B[SW(o + 1)] = pk2(cmul(w1, x1), cmul(w1, z1));
    B[SW(o + 2)] = pk2(cmul(w2, x2), cmul(w2, z2));
    B[SW(o + 3)] = pk2(cmul(w3, x3), cmul(w3, z3));
  }
  LBAR();

  stage_pair(B, A, t, 2); LBAR();
  stage_pair(A, B, t, 4); LBAR();
  stage_pair(B, A, t, 6); LBAR();
  {
    const float4 va = A[SW(t)];
    const float4 vb = A[SW(t + 256)];
    const float4 vc = A[SW(t + 512)];
    const float4 vd = A[SW(t + 768)];
    const float2 pa0 = mkC(va.x, va.y), pa1 = mkC(va.z, va.w);
    const float2 pb0 = mkC(vb.x, vb.y), pb1 = mkC(vb.z, vb.w);
    const float2 pc0 = mkC(vc.x, vc.y), pc1 = mkC(vc.z, vc.w);
    const float2 pd0 = mkC(vd.x, vd.y), pd1 = mkC(vd.z, vd.w);
    float2 x0, x1, x2, x3, z0, z1, z2, z3;
    BF4(pa0, pb0, pc0, pd0, x0, x1, x2, x3);
    BF4(pa1, pb1, pc1, pd1, z0, z1, z2, z3);
    yr0[t] = pack_out(x0);       yr1[t] = pack_out(z0);
    yr0[t + 256] = pack_out(x1); yr1[t + 256] = pack_out(z1);
    yr0[t + 512] = pack_out(x2); yr1[t + 512] = pack_out(z2);
    yr0[t + 768] = pack_out(x3); yr1[t + 768] = pack_out(z3);
  }
}

// ---------------- K2b: y (B,C,L) bf16 -> yt (B,L,C) bf16 ----------------
__global__ __launch_bounds__(256) void transpose_y(
    const u16* __restrict__ y, u16* __restrict__ yt) {
  __shared__ u16 tile[64][80];
  const int b = blockIdx.z;
  const int tb = blockIdx.x * 64;
  const int cb = blockIdx.y * 64;
  const int tid = threadIdx.x;
  {
    const int tl = (tid & 7) * 8;
    const int cl = tid >> 3;
    #pragma unroll
    for (int h = 0; h < 2; ++h) {
      const int cc = cl + h * 32;
      const u16x8 v = *(const u16x8*)(y + ((size_t)(b * 512 + cb + cc)) * 2048 + tb + tl);
      #pragma unroll
      for (int i = 0; i < 8; ++i) tile[cc][tl + i] = v[i];
    }
  }
  __syncthreads();
  {
    const int c2 = (tid & 7) * 8;
    const int t2 = tid >> 3;
    #pragma unroll
    for (int h = 0; h < 2; ++h) {
      const int tt = t2 + h * 32;
      u16 tmp[8];
      #pragma unroll
      for (int i = 0; i < 8; ++i) tmp[i] = tile[c2 + i][tt];
      *(u16x8*)(yt + ((size_t)(b * 2048 + tb + tt)) * 512 + cb + c2) = *(u16x8*)tmp;
    }
  }
}

// ---------------- K3: 256x128x(K=512) 8-phase GEMM + GLU, BK=32 ----------------
// 8 waves (4M x 2N), 64x64 per wave; LDS 48KB -> 2 blocks/CU; acc[4][4]=64 VGPR.
// A[2buf][2half][128 rows][32 k] u16 (8192/buf); B[2buf][128 t][32 k] (4096/buf).
// Swizzle: 16B slot = lq ^ (row&3), row&3 == lrow&3 on reads (lane-const).
#define FRAG_A(P, Q) __builtin_bit_cast(short8, *(const u16x8*)&lds[           \
    (P) * 8192 + hA4096 + (rA + (Q) * 16) * 32 + csA])
#define FRAG_B(P, NI) __builtin_bit_cast(short8, *(const u16x8*)&lds[          \
    16384 + (P) * 4096 + (rB + (NI) * 16) * 32 + csA])

#define STAGE_A(KT, H, P) do {                                                 \
    const int sr_ = m0 + (H) * 128 + rowg;                                     \
    const int o_ = (sr_ & 1) ? (512 + (sr_ >> 1)) : (sr_ >> 1);                \
    gload_lds16(Wb + (size_t)o_ * 512 + (KT) * 32 + srcsw,                     \
                lds + (P) * 8192 + (H) * 4096 + wq * 512);                     \
  } while (0)
#define STAGE_B2(KT, P) do {                                                   \
    gload_lds16(yt + ((size_t)(bb * 2048 + t0b + rowg)) * 512 + (KT) * 32 +    \
                    srcsw,                                                     \
                lds + 16384 + (P) * 4096 + wq * 512);                          \
  } while (0)

#define PHASE_CORE(Q, READS, STAGES, VWAIT)                                    \
  {                                                                            \
    short8 aq = FRAG_A(PP, Q);                                                 \
    READS;                                                                     \
    STAGES;                                                                    \
    __builtin_amdgcn_s_barrier();                                              \
    asm volatile("s_waitcnt lgkmcnt(0)" ::: "memory");                         \
    __builtin_amdgcn_sched_barrier(0);                                         \
    __builtin_amdgcn_s_setprio(1);                                             \
    acc[Q][0] = __builtin_amdgcn_mfma_f32_16x16x32_bf16(aq, br[0], acc[Q][0], 0, 0, 0); \
    acc[Q][1] = __builtin_amdgcn_mfma_f32_16x16x32_bf16(aq, br[1], acc[Q][1], 0, 0, 0); \
    acc[Q][2] = __builtin_amdgcn_mfma_f32_16x16x32_bf16(aq, br[2], acc[Q][2], 0, 0, 0); \
    acc[Q][3] = __builtin_amdgcn_mfma_f32_16x16x32_bf16(aq, br[3], acc[Q][3], 0, 0, 0); \
    __builtin_amdgcn_s_setprio(0);                                             \
    __builtin_amdgcn_sched_barrier(0);                                         \
    VWAIT;                                                                     \
    __builtin_amdgcn_s_barrier();                                              \
  }

#define READ_B(P) do {                                                         \
    br[0] = FRAG_B(P, 0);                                                      \
    br[1] = FRAG_B(P, 1);                                                      \
    br[2] = FRAG_B(P, 2);                                                      \
    br[3] = FRAG_B(P, 3);                                                      \
  } while (0)

__global__ __launch_bounds__(512, 2) void gemm_glu(
    const u16* __restrict__ Wb, const u16* __restrict__ yt,
    const float* __restrict__ bias, float* __restrict__ out) {
  extern __shared__ __align__(16) u16 lds[];
  const int bid = blockIdx.x;
  const int wg = (bid & 7) * 128 + (bid >> 3);  // XCD swizzle (1024 = 8*128)
  const int bb = wg >> 6;                       // batch
  const int mt = (wg >> 4) & 3;
  const int nt = wg & 15;
  const int m0 = mt * 256;
  const int t0b = nt * 128;
  const int tid = threadIdx.x;
  const int lane = tid & 63;
  const int wq = tid >> 6;                      // wave 0..7
  const int wm = wq >> 1, wn = wq & 1;          // 4 M-waves x 2 N-waves
  const int lrow = lane & 15, lq = lane >> 4;
  const int csA = (lq ^ (lrow & 3)) << 3;       // swizzled 16B slot (u16 units)
  const int hA4096 = (wm >> 1) * 4096;
  const int rA = (wm & 1) * 64 + lrow;
  const int rB = wn * 64 + lrow;
  const int rowg = tid >> 2;                    // staging granule row
  const int srcsw = (((tid & 3) ^ ((tid >> 2) & 3)) << 3);  // staging src k-off

  f32x4 acc[4][4];
  const f32x4 z4 = {0.f, 0.f, 0.f, 0.f};
  #pragma unroll
  for (int mi = 0; mi < 4; ++mi)
    #pragma unroll
    for (int ni = 0; ni < 4; ++ni) acc[mi][ni] = z4;
  short8 br[4];

  // prologue: tile0 A(2)+B(1) -> buf0, tile1 B(1) -> buf1
  STAGE_A(0, 0, 0); STAGE_A(0, 1, 0); STAGE_B2(0, 0);
  STAGE_B2(1, 1);
  asm volatile("s_waitcnt vmcnt(1)" ::: "memory");  // tile0's 3 loads landed
  __builtin_amdgcn_s_barrier();

  #pragma unroll
  for (int j = 0; j < 8; ++j) {
    const int e2 = 2 * j + 2, o1 = 2 * j + 1, o3 = 2 * j + 3;
    #define PP 0
    PHASE_CORE(0, READ_B(0), STAGE_A(o1, 0, 1), )
    PHASE_CORE(1, , STAGE_A(o1, 1, 1), )
    PHASE_CORE(2, , if (j < 7) STAGE_B2(e2, 0), )
    PHASE_CORE(3, , ,
               if (j < 7) { asm volatile("s_waitcnt vmcnt(1)" ::: "memory"); }
               else { asm volatile("s_waitcnt vmcnt(0)" ::: "memory"); })
    #undef PP
    #define PP 1
    PHASE_CORE(0, READ_B(1), if (j < 7) STAGE_A(e2, 0, 0), )
    PHASE_CORE(1, , if (j < 7) STAGE_A(e2, 1, 0), )
    PHASE_CORE(2, , if (j < 7) STAGE_B2(o3, 1), )
    PHASE_CORE(3, , ,
               if (j < 7) { asm volatile("s_waitcnt vmcnt(1)" ::: "memory"); })
    #undef PP
  }

  #pragma unroll
  for (int mi = 0; mi < 4; ++mi) {
    const int sr0 = m0 + wm * 64 + mi * 16 + lq * 4;  // even stack row
    const int ch = sr0 >> 1;
    const float ba0 = bias[ch],     bg0 = bias[512 + ch];
    const float ba1 = bias[ch + 1], bg1 = bias[512 + ch + 1];
    #pragma unroll
    for (int ni = 0; ni < 4; ++ni) {
      const int t = t0b + wn * 64 + ni * 16 + (lane & 15);
      const f32x4 v = acc[mi][ni];
      const float a0 = v[0] + ba0, g0 = v[1] + bg0;
      const float a1 = v[2] + ba1, g1 = v[3] + bg1;
      out[((size_t)(bb * 512 + ch)) * 2048 + t]     = a0 * RCP(1.f + __expf(-g0));
      out[((size_t)(bb * 512 + ch + 1)) * 2048 + t] = a1 * RCP(1.f + __expf(-g1));
    }
  }
}

extern "C" void kernel_launch(void* const* d_in, const int* in_sizes, int n_in,
                              void* d_out, int out_size, void* d_ws, size_t ws_size,
                              hipStream_t stream) {
  (void)in_sizes; (void)n_in; (void)out_size; (void)ws_size;
  const float* u      = (const float*)d_in[0];
  const float* log_dt = (const float*)d_in[1];
  const float* Hr     = (const float*)d_in[2];
  const float* Hi     = (const float*)d_in[3];
  const float* Dv     = (const float*)d_in[4];
  const float* W      = (const float*)d_in[5];
  const float* bias   = (const float*)d_in[6];

  char* ws = (char*)d_ws;
  float2* kep = (float2*)(ws);                     // 8.4 MB
  u16*    Wb  = (u16*)  (ws + ((size_t)9 << 20));  // 1 MB
  u16*    yt  = (u16*)  (ws + ((size_t)12 << 20)); // 32 MB
  u16*    ybf = (u16*)d_out;                       // bf16 y staged in d_out

  build_kep<<<dim3(512), 512, 0, stream>>>(log_dt, Hr, Hi, Dv, W, kep, Wb);
  fft_conv<<<dim3(8, 512), 256, 0, stream>>>(u, kep, ybf);
  transpose_y<<<dim3(32, 8, 16), 256, 0, stream>>>(ybf, yt);
  gemm_glu<<<dim3(1024), 512, 49152, stream>>>(Wb, yt, bias, (float*)d_out);
}

// Round 18
// 129.099 us; speedup vs baseline: 1.0222x; 1.0222x over previous
//
#include <hip/hip_runtime.h>
#include <math.h>

typedef unsigned short u16;
typedef unsigned int u32;
typedef __attribute__((ext_vector_type(8))) short short8;
typedef __attribute__((ext_vector_type(8))) u16 u16x8;
typedef __attribute__((ext_vector_type(4))) float f32x4;

#define SW(i) ((i) ^ (((i) >> 4) & 15))

#if __has_builtin(__builtin_amdgcn_rcpf)
#define RCP(x) __builtin_amdgcn_rcpf(x)
#else
#define RCP(x) (1.0f / (x))
#endif

#define LBAR()                                                                 \
  do {                                                                         \
    asm volatile("s_waitcnt lgkmcnt(0)" ::: "memory");                         \
    __builtin_amdgcn_s_barrier();                                              \
    __builtin_amdgcn_sched_barrier(0);                                         \
  } while (0)

static __device__ __forceinline__ u16 f2bf(float x) {
  unsigned u = __builtin_bit_cast(unsigned, x);
  return (u16)((u + 0x7FFFu + ((u >> 16) & 1u)) >> 16);
}

static __device__ __forceinline__ float2 cmul(float2 a, float2 b) {
  return make_float2(a.x * b.x - a.y * b.y, a.x * b.y + a.y * b.x);
}
static __device__ __forceinline__ float2 cadd(float2 a, float2 b) {
  return make_float2(a.x + b.x, a.y + b.y);
}
static __device__ __forceinline__ float2 conjf2(float2 a) {
  return make_float2(a.x, -a.y);
}
static __device__ __forceinline__ float2 mkC(float a, float b) {
  return make_float2(a, b);
}
static __device__ __forceinline__ float4 pk2(float2 p, float2 q) {
  return make_float4(p.x, p.y, q.x, q.y);
}

static __device__ __forceinline__ float2 twd(int j) {
  float s, c;
  __sincosf((float)j * -0.00613592315154256492f, &s, &c);
  return make_float2(c, s);
}

static __device__ __forceinline__ float gelu_fast(float y) {
  const float t = __builtin_fmaf(0.044715f * y * y, y, y);
  const float e = __expf(-1.5957691216f * t);
  return y * RCP(1.f + e);
}

static __device__ __forceinline__ u32 pack_out(float2 r) {
  const u32 lo = f2bf(gelu_fast(r.x));
  const u32 hi = f2bf(gelu_fast(-r.y));
  return lo | (hi << 16);
}

static __device__ __forceinline__ void gload_lds16(const void* g, void* l) {
  __builtin_amdgcn_global_load_lds(
      (const __attribute__((address_space(1))) u32*)g,
      (__attribute__((address_space(3))) u32*)l, 16, 0, 0);
}

#define BF4(A, B, C, D, Y0, Y1, Y2, Y3)                                        \
  {                                                                            \
    const float apcr = (A).x + (C).x, apci = (A).y + (C).y;                    \
    const float amcr = (A).x - (C).x, amci = (A).y - (C).y;                    \
    const float bpdr = (B).x + (D).x, bpdi = (B).y + (D).y;                    \
    const float bmdr = (B).x - (D).x, bmdi = (B).y - (D).y;                    \
    Y0 = make_float2(apcr + bpdr, apci + bpdi);                                \
    Y2 = make_float2(apcr - bpdr, apci - bpdi);                                \
    Y1 = make_float2(amcr + bmdi, amci - bmdr);                                \
    Y3 = make_float2(amcr - bmdi, amci + bmdr);                                \
  }

// ---------------- K1: merged hope-kernel + filter coeffs (+D folded) + W->bf16
static __device__ __forceinline__ void hope_sum(
    const float* __restrict__ log_dt, const float* __restrict__ Hr,
    const float* __restrict__ Hi, int h, int l, float* outr, float* outi) {
  const float dt = expf(log_dt[h]);
  const float phi = 6.28318530717958647692f * (float)l * (1.0f / 1024.0f);
  float sphi, cphi;
  sincosf(phi, &sphi, &cphi);
  const float nr = (1.f + dt) * cphi + dt - 1.f;
  const float ni = (1.f + dt) * sphi;
  const float dr = (dt - 1.f) * cphi + dt + 1.f;
  const float di = (dt - 1.f) * sphi;
  const float theta = atan2f(ni * dr - nr * di, nr * dr + ni * di);
  float sw, cw;
  sincosf(theta, &sw, &cw);
  const float wr = cw, wi = -sw;  // e^{-i theta}
  float cr = wr, ci = wi;
  float ar = 0.f, ai = 0.f;
  const float* __restrict__ hr = Hr + h * 64;
  const float* __restrict__ hi = Hi + h * 64;
  for (int n = 0; n < 64; ++n) {
    const float a = hr[n], bb = hi[n];
    ar += a * cr - bb * ci;
    ai += a * ci + bb * cr;
    const float t = cr * wr - ci * wi;
    ci = cr * wi + ci * wr;
    cr = t;
  }
  *outr = ar;
  *outi = ai;
}

__global__ __launch_bounds__(512) void build_kep(
    const float* __restrict__ log_dt, const float* __restrict__ Hr,
    const float* __restrict__ Hi, const float* __restrict__ Dv,
    const float* __restrict__ W, float2* __restrict__ kep,
    u16* __restrict__ Wb) {
  __shared__ float2 K1[1024], K2[1024];
  const int c = blockIdx.x;
  const int t = threadIdx.x;
  Wb[c * 1024 + t] = f2bf(W[c * 1024 + t]);
  Wb[c * 1024 + 512 + t] = f2bf(W[c * 1024 + 512 + t]);
  float r, i;
  hope_sum(log_dt, Hr, Hi, c, t, &r, &i);             K1[t] = make_float2(r, i);
  hope_sum(log_dt, Hr, Hi, c, t + 512, &r, &i);       K1[t + 512] = make_float2(r, i);
  hope_sum(log_dt, Hr, Hi, c + 512, t, &r, &i);       K2[t] = make_float2(r, i);
  hope_sum(log_dt, Hr, Hi, c + 512, t + 512, &r, &i); K2[t + 512] = make_float2(r, i);
  __syncthreads();
  const float s = 1.0f / 2048.0f;
  const float dcs = Dv[c] * s;
  for (int q = t; q <= 512; q += 512) {
    float2 kf, kg;
    {
      const int qa = q;
      kf = (qa == 0) ? make_float2(K1[0].x * s, 0.f)
                     : make_float2(0.5f * s * (K1[qa].x + K2[qa - 1].x),
                                   0.5f * s * (K1[qa].y - K2[qa - 1].y));
      const int qb = 1024 - q;
      kg = (qb == 1024) ? make_float2(K2[1023].x * s, 0.f)
           : (qb == 0)  ? make_float2(K1[0].x * s, 0.f)
                        : make_float2(0.5f * s * (K1[qb].x + K2[qb - 1].x),
                                      0.5f * s * (K1[qb].y - K2[qb - 1].y));
    }
    kf.x += dcs;
    kg.x += dcs;
    float2 C1, C2, C3, C4;
    if (q == 0) {
      C1 = make_float2(kf.x + kg.x, kg.y - kf.y);
      C2 = make_float2(-(kg.y + kf.y), kg.x - kf.x);
      C3 = C2;
      C4 = C1;
    } else {
      float st, ct;
      sincosf(3.14159265358979323846f * (float)q * (1.f / 1024.f), &st, &ct);
      const float2 A1 = make_float2(1.f - st, -ct);
      const float2 A2 = make_float2(1.f + st, ct);
      const float2 kgc = make_float2(kg.x, -kg.y);
      const float2 t1 = cmul(kf, A1), t2 = cmul(kgc, A2);
      const float2 t3 = cmul(kf, A2), t4 = cmul(kgc, A1);
      const float2 p1 = make_float2(0.5f * (t1.x + t2.x), 0.5f * (t1.y + t2.y));
      const float2 p2 = make_float2(0.5f * (t3.x + t4.x), 0.5f * (t3.y + t4.y));
      const float2 q1 = make_float2(0.5f * (t1.x - t2.x), 0.5f * (t1.y - t2.y));
      const float2 q2 = make_float2(0.5f * (t3.x - t4.x), 0.5f * (t3.y - t4.y));
      const float2 iWc = make_float2(-st, ct);
      const float2 r1 = cmul(iWc, q1), r2 = cmul(iWc, q2);
      C1 = make_float2(p1.x + r1.x, -(p1.y + r1.y));
      C2 = make_float2(p2.x + r2.x, -(p2.y + r2.y));
      C3 = make_float2(p1.x - r1.x, p1.y - r1.y);
      C4 = make_float2(p2.x - r2.x, p2.y - r2.y);
    }
    float2* o = kep + ((size_t)c * 513 + q) * 4;
    o[0] = C1; o[1] = C2; o[2] = C3; o[3] = C4;
  }
}

// ------- K2: Stockham rfft-conv (R16 structure, unchanged) --------------------
static __device__ __forceinline__ void stage_pair(
    const float4* __restrict__ S, float4* __restrict__ D, int t, int sh) {
  const int m = 1 << sh;
  const int kk = t & (m - 1);
  const int o = kk + ((t >> sh) << (sh + 2));
  const float4 va = S[SW(t)];
  const float4 vb = S[SW(t + 256)];
  const float4 vc = S[SW(t + 512)];
  const float4 vd = S[SW(t + 768)];
  const float2 a0 = mkC(va.x, va.y), a1 = mkC(va.z, va.w);
  const float2 b0 = mkC(vb.x, vb.y), b1 = mkC(vb.z, vb.w);
  const float2 c0 = mkC(vc.x, vc.y), c1 = mkC(vc.z, vc.w);
  const float2 d0 = mkC(vd.x, vd.y), d1 = mkC(vd.z, vd.w);
  float2 x0, x1, x2, x3, z0, z1, z2, z3;
  BF4(a0, b0, c0, d0, x0, x1, x2, x3);
  BF4(a1, b1, c1, d1, z0, z1, z2, z3);
  const float2 w1 = twd((t >> sh) << sh);
  const float2 w2 = cmul(w1, w1);
  const float2 w3 = cmul(w2, w1);
  D[SW(o)] = pk2(x0, z0);
  D[SW(o + m)] = pk2(cmul(w1, x1), cmul(w1, z1));
  D[SW(o + 2 * m)] = pk2(cmul(w2, x2), cmul(w2, z2));
  D[SW(o + 3 * m)] = pk2(cmul(w3, x3), cmul(w3, z3));
}

static __device__ __forceinline__ void stage_pair_last(
    const float4* __restrict__ S, float4* __restrict__ D, int t) {
  const float4 va = S[SW(t)];
  const float4 vb = S[SW(t + 256)];
  const float4 vc = S[SW(t + 512)];
  const float4 vd = S[SW(t + 768)];
  const float2 a0 = mkC(va.x, va.y), a1 = mkC(va.z, va.w);
  const float2 b0 = mkC(vb.x, vb.y), b1 = mkC(vb.z, vb.w);
  const float2 c0 = mkC(vc.x, vc.y), c1 = mkC(vc.z, vc.w);
  const float2 d0 = mkC(vd.x, vd.y), d1 = mkC(vd.z, vd.w);
  float2 x0, x1, x2, x3, z0, z1, z2, z3;
  BF4(a0, b0, c0, d0, x0, x1, x2, x3);
  BF4(a1, b1, c1, d1, z0, z1, z2, z3);
  D[SW(t)] = pk2(x0, z0);
  D[SW(t + 256)] = pk2(x1, z1);
  D[SW(t + 512)] = pk2(x2, z2);
  D[SW(t + 768)] = pk2(x3, z3);
}

__global__ __launch_bounds__(256) void fft_conv(
    const float* __restrict__ u, const float2* __restrict__ kep,
    u16* __restrict__ y) {
  __shared__ float4 bufA[1024], bufB[1024];  // 32768 B
  const int bq = blockIdx.x, c = blockIdx.y;
  const int t = threadIdx.x;

  const float4* __restrict__ krow4 = (const float4*)(kep + (size_t)c * (513 * 4));
  const float4 cA0 = krow4[2 * t];
  const float4 cA1 = krow4[2 * (t + 256)];
  const float4 cC  = krow4[2 * (512 - t) + 1];
  const float4 cDq = krow4[2 * (256 - t) + 1];
  const float4 cM  = krow4[1024];

  const int b0 = bq * 2, b1 = bq * 2 + 1;
  const float2* __restrict__ u20 = (const float2*)(u + ((size_t)(b0 * 512 + c)) * 2048);
  const float2* __restrict__ u21 = (const float2*)(u + ((size_t)(b1 * 512 + c)) * 2048);
  u32* __restrict__ yr0 = (u32*)(y + ((size_t)(b0 * 512 + c)) * 2048);
  u32* __restrict__ yr1 = (u32*)(y + ((size_t)(b1 * 512 + c)) * 2048);
  float4* A = bufA;
  float4* B = bufB;

  {
    float2 v0[4], v1[4];
    #pragma unroll
    for (int q = 0; q < 4; ++q) {
      v0[q] = u20[t + 256 * q];
      v1[q] = u21[t + 256 * q];
    }
    float2 x0, x1, x2, x3, z0, z1, z2, z3;
    BF4(v0[0], v0[1], v0[2], v0[3], x0, x1, x2, x3);
    BF4(v1[0], v1[1], v1[2], v1[3], z0, z1, z2, z3);
    const float2 w1 = twd(t);
    const float2 w2 = cmul(w1, w1);
    const float2 w3 = cmul(w2, w1);
    const int o = 4 * t;
    A[SW(o)] = pk2(x0, z0);
    A[SW(o + 1)] = pk2(cmul(w1, x1), cmul(w1, z1));
    A[SW(o + 2)] = pk2(cmul(w2, x2), cmul(w2, z2));
    A[SW(o + 3)] = pk2(cmul(w3, x3), cmul(w3, z3));
  }
  LBAR();
  stage_pair(A, B, t, 2); LBAR();
  stage_pair(B, A, t, 4); LBAR();
  stage_pair(A, B, t, 6); LBAR();
  stage_pair_last(B, A, t); LBAR();

  {
    const int gp0 = (1024 - t) & 1023;
    const float2 w1 = twd(t);
    const float2 w2 = cmul(w1, w1);
    const float2 w3 = cmul(w2, w1);
    const int o = 4 * t;
    const float4 Vf0 = A[SW(t)],       Vg0 = A[SW(gp0)];
    const float4 Vf1 = A[SW(t + 256)], Vg1 = A[SW(768 - t)];
    const float4 Vc  = A[SW(t + 512)], Vcf = A[SW(512 - t)];
    const float4 Vd  = A[SW(t + 768)], Vdf = A[SW(256 - t)];
    const float2 CA1 = mkC(cA0.x, cA0.y), CA2 = mkC(cA0.z, cA0.w);
    const float2 CB1 = mkC(cA1.x, cA1.y), CB2 = mkC(cA1.z, cA1.w);
    const float2 CC3 = mkC(cC.x, cC.y),   CC4 = mkC(cC.z, cC.w);
    const float2 CD3 = mkC(cDq.x, cDq.y), CD4 = mkC(cDq.z, cDq.w);
    const float2 CM1 = mkC(cM.x, cM.y),   CM2 = mkC(cM.z, cM.w);
    float2 Da0, Da1, Db0, Db1, Dc0, Dc1, Dd0, Dd1;
    Da0 = cadd(cmul(CA1, conjf2(mkC(Vf0.x, Vf0.y))), cmul(CA2, mkC(Vg0.x, Vg0.y)));
    Da1 = cadd(cmul(CA1, conjf2(mkC(Vf0.z, Vf0.w))), cmul(CA2, mkC(Vg0.z, Vg0.w)));
    Db0 = cadd(cmul(CB1, conjf2(mkC(Vf1.x, Vf1.y))), cmul(CB2, mkC(Vg1.x, Vg1.y)));
    Db1 = cadd(cmul(CB1, conjf2(mkC(Vf1.z, Vf1.w))), cmul(CB2, mkC(Vg1.z, Vg1.w)));
    if (t == 0) {
      Dc0 = cadd(cmul(CM1, conjf2(mkC(Vc.x, Vc.y))), cmul(CM2, mkC(Vc.x, Vc.y)));
      Dc1 = cadd(cmul(CM1, conjf2(mkC(Vc.z, Vc.w))), cmul(CM2, mkC(Vc.z, Vc.w)));
    } else {
      Dc0 = cadd(cmul(CC3, mkC(Vcf.x, Vcf.y)), cmul(CC4, conjf2(mkC(Vc.x, Vc.y))));
      Dc1 = cadd(cmul(CC3, mkC(Vcf.z, Vcf.w)), cmul(CC4, conjf2(mkC(Vc.z, Vc.w))));
    }
    Dd0 = cadd(cmul(CD3, mkC(Vdf.x, Vdf.y)), cmul(CD4, conjf2(mkC(Vd.x, Vd.y))));
    Dd1 = cadd(cmul(CD3, mkC(Vdf.z, Vdf.w)), cmul(CD4, conjf2(mkC(Vd.z, Vd.w))));
    float2 x0, x1, x2, x3, z0, z1, z2, z3;
    BF4(Da0, Db0, Dc0, Dd0, x0, x1, x2, x3);
    BF4(Da1, Db1, Dc1, Dd1, z0, z1, z2, z3);
    B[SW(o)] = pk2(x0, z0);
    B[SW(o + 1)] = pk2(cmul(w1, x1), cmul(w1, z1));
    B[SW(o + 2)] = pk2(cmul(w2, x2), cmul(w2, z2));
    B[SW(o + 3)] = pk2(cmul(w3, x3), cmul(w3, z3));
  }
  LBAR();

  stage_pair(B, A, t, 2); LBAR();
  stage_pair(A, B, t, 4); LBAR();
  stage_pair(B, A, t, 6); LBAR();
  {
    const float4 va = A[SW(t)];
    const float4 vb = A[SW(t + 256)];
    const float4 vc = A[SW(t + 512)];
    const float4 vd = A[SW(t + 768)];
    const float2 pa0 = mkC(va.x, va.y), pa1 = mkC(va.z, va.w);
    const float2 pb0 = mkC(vb.x, vb.y), pb1 = mkC(vb.z, vb.w);
    const float2 pc0 = mkC(vc.x, vc.y), pc1 = mkC(vc.z, vc.w);
    const float2 pd0 = mkC(vd.x, vd.y), pd1 = mkC(vd.z, vd.w);
    float2 x0, x1, x2, x3, z0, z1, z2, z3;
    BF4(pa0, pb0, pc0, pd0, x0, x1, x2, x3);
    BF4(pa1, pb1, pc1, pd1, z0, z1, z2, z3);
    yr0[t] = pack_out(x0);       yr1[t] = pack_out(z0);
    yr0[t + 256] = pack_out(x1); yr1[t + 256] = pack_out(z1);
    yr0[t + 512] = pack_out(x2); yr1[t + 512] = pack_out(z2);
    yr0[t + 768] = pack_out(x3); yr1[t + 768] = pack_out(z3);
  }
}

// ---------------- K2b: y (B,C,L) bf16 -> yt (B,L,C) bf16 ----------------
__global__ __launch_bounds__(256) void transpose_y(
    const u16* __restrict__ y, u16* __restrict__ yt) {
  __shared__ u16 tile[64][80];
  const int b = blockIdx.z;
  const int tb = blockIdx.x * 64;
  const int cb = blockIdx.y * 64;
  const int tid = threadIdx.x;
  {
    const int tl = (tid & 7) * 8;
    const int cl = tid >> 3;
    #pragma unroll
    for (int h = 0; h < 2; ++h) {
      const int cc = cl + h * 32;
      const u16x8 v = *(const u16x8*)(y + ((size_t)(b * 512 + cb + cc)) * 2048 + tb + tl);
      #pragma unroll
      for (int i = 0; i < 8; ++i) tile[cc][tl + i] = v[i];
    }
  }
  __syncthreads();
  {
    const int c2 = (tid & 7) * 8;
    const int t2 = tid >> 3;
    #pragma unroll
    for (int h = 0; h < 2; ++h) {
      const int tt = t2 + h * 32;
      u16 tmp[8];
      #pragma unroll
      for (int i = 0; i < 8; ++i) tmp[i] = tile[c2 + i][tt];
      *(u16x8*)(yt + ((size_t)(b * 2048 + tb + tt)) * 512 + cb + c2) = *(u16x8*)tmp;
    }
  }
}

// ----- K3: 256x256x(K=512) GEMM + GLU; BK=32, 1024 thr (16 waves of 64x64) ----
// LDS 64KB (2buf x (A 16KB + B 16KB)); 1 barrier + 16 MFMA per wave per K-tile.
// Swizzle: 16B slot = lq ^ (row&3); staging source pre-swizzled (involution).
#define FRAG_A(P, MI) __builtin_bit_cast(short8, *(const u16x8*)&lds[          \
    (P) * 8192 + (rA + (MI) * 16) * 32 + csA])
#define FRAG_B(P, NI) __builtin_bit_cast(short8, *(const u16x8*)&lds[          \
    16384 + (P) * 8192 + (rB + (NI) * 16) * 32 + csA])

#define STAGE_A(KT, P) do {                                                    \
    const int sr_ = m0 + rowg;                                                 \
    const int o_ = (sr_ & 1) ? (512 + (sr_ >> 1)) : (sr_ >> 1);                \
    gload_lds16(Wb + (size_t)o_ * 512 + (KT) * 32 + srcsw,                     \
                lds + (P) * 8192 + wq * 512);                                  \
  } while (0)
#define STAGE_B2(KT, P) do {                                                   \
    gload_lds16(yt + ((size_t)(bb * 2048 + t0b + rowg)) * 512 + (KT) * 32 +    \
                    srcsw,                                                     \
                lds + 16384 + (P) * 8192 + wq * 512);                          \
  } while (0)

__global__ __launch_bounds__(1024, 4) void gemm_glu(
    const u16* __restrict__ Wb, const u16* __restrict__ yt,
    const float* __restrict__ bias, float* __restrict__ out) {
  extern __shared__ __align__(16) u16 lds[];
  const int bid = blockIdx.x;
  const int wg = (bid & 7) * 64 + (bid >> 3);  // XCD swizzle (512 = 8*64)
  const int bb = wg >> 5;                      // batch
  const int mt = (wg >> 3) & 3;
  const int nt = wg & 7;
  const int m0 = mt * 256;
  const int t0b = nt * 256;
  const int tid = threadIdx.x;
  const int lane = tid & 63;
  const int wq = tid >> 6;                     // wave 0..15
  const int wm = wq >> 2, wn = wq & 3;         // 4 M-waves x 4 N-waves
  const int lrow = lane & 15, lq = lane >> 4;
  const int csA = (lq ^ (lrow & 3)) << 3;      // fragment 16B slot (u16 units)
  const int rA = wm * 64 + lrow;
  const int rB = wn * 64 + lrow;
  const int rowg = tid >> 2;                   // staging row 0..255
  const int srcsw = (((tid & 3) ^ (rowg & 3)) << 3);  // staging src k-offset

  f32x4 acc[4][4];
  const f32x4 z4 = {0.f, 0.f, 0.f, 0.f};
  #pragma unroll
  for (int mi = 0; mi < 4; ++mi)
    #pragma unroll
    for (int ni = 0; ni < 4; ++ni) acc[mi][ni] = z4;

  // prologue: tile0 -> buf0
  STAGE_A(0, 0); STAGE_B2(0, 0);
  asm volatile("s_waitcnt vmcnt(0)" ::: "memory");
  __builtin_amdgcn_s_barrier();

  #pragma unroll
  for (int j = 0; j < 16; ++j) {
    const int P = j & 1;
    short8 af[4], bf[4];
    #pragma unroll
    for (int mi = 0; mi < 4; ++mi) af[mi] = FRAG_A(P, mi);
    #pragma unroll
    for (int ni = 0; ni < 4; ++ni) bf[ni] = FRAG_B(P, ni);
    if (j < 15) { STAGE_A(j + 1, P ^ 1); STAGE_B2(j + 1, P ^ 1); }
    asm volatile("s_waitcnt lgkmcnt(0)" ::: "memory");
    __builtin_amdgcn_sched_barrier(0);
    __builtin_amdgcn_s_setprio(1);
    #pragma unroll
    for (int mi = 0; mi < 4; ++mi)
      #pragma unroll
      for (int ni = 0; ni < 4; ++ni)
        acc[mi][ni] = __builtin_amdgcn_mfma_f32_16x16x32_bf16(af[mi], bf[ni],
                                                              acc[mi][ni], 0, 0, 0);
    __builtin_amdgcn_s_setprio(0);
    __builtin_amdgcn_sched_barrier(0);
    if (j < 15) { asm volatile("s_waitcnt vmcnt(0)" ::: "memory"); }
    __builtin_amdgcn_s_barrier();
  }

  #pragma unroll
  for (int mi = 0; mi < 4; ++mi) {
    const int sr0 = m0 + wm * 64 + mi * 16 + lq * 4;  // even stack row
    const int ch = sr0 >> 1;
    const float ba0 = bias[ch],     bg0 = bias[512 + ch];
    const float ba1 = bias[ch + 1], bg1 = bias[512 + ch + 1];
    #pragma unroll
    for (int ni = 0; ni < 4; ++ni) {
      const int t = t0b + wn * 64 + ni * 16 + lrow;
      const f32x4 v = acc[mi][ni];
      const float a0 = v[0] + ba0, g0 = v[1] + bg0;
      const float a1 = v[2] + ba1, g1 = v[3] + bg1;
      out[((size_t)(bb * 512 + ch)) * 2048 + t]     = a0 * RCP(1.f + __expf(-g0));
      out[((size_t)(bb * 512 + ch + 1)) * 2048 + t] = a1 * RCP(1.f + __expf(-g1));
    }
  }
}

extern "C" void kernel_launch(void* const* d_in, const int* in_sizes, int n_in,
                              void* d_out, int out_size, void* d_ws, size_t ws_size,
                              hipStream_t stream) {
  (void)in_sizes; (void)n_in; (void)out_size; (void)ws_size;
  const float* u      = (const float*)d_in[0];
  const float* log_dt = (const float*)d_in[1];
  const float* Hr     = (const float*)d_in[2];
  const float* Hi     = (const float*)d_in[3];
  const float* Dv     = (const float*)d_in[4];
  const float* W      = (const float*)d_in[5];
  const float* bias   = (const float*)d_in[6];

  char* ws = (char*)d_ws;
  float2* kep = (float2*)(ws);                     // 8.4 MB
  u16*    Wb  = (u16*)  (ws + ((size_t)9 << 20));  // 1 MB
  u16*    yt  = (u16*)  (ws + ((size_t)12 << 20)); // 32 MB
  u16*    ybf = (u16*)d_out;                       // bf16 y staged in d_out

  build_kep<<<dim3(512), 512, 0, stream>>>(log_dt, Hr, Hi, Dv, W, kep, Wb);
  fft_conv<<<dim3(8, 512), 256, 0, stream>>>(u, kep, ybf);
  transpose_y<<<dim3(32, 8, 16), 256, 0, stream>>>(ybf, yt);
  gemm_glu<<<dim3(512), 1024, 65536, stream>>>(Wb, yt, bias, (float*)d_out);
}

// Round 19
// 124.276 us; speedup vs baseline: 1.0619x; 1.0388x over previous
//
#include <hip/hip_runtime.h>
#include <math.h>

typedef unsigned short u16;
typedef unsigned int u32;
typedef __attribute__((ext_vector_type(8))) short short8;
typedef __attribute__((ext_vector_type(8))) u16 u16x8;
typedef __attribute__((ext_vector_type(4))) float f32x4;

#define SW(i) ((i) ^ (((i) >> 4) & 15))

#if __has_builtin(__builtin_amdgcn_rcpf)
#define RCP(x) __builtin_amdgcn_rcpf(x)
#else
#define RCP(x) (1.0f / (x))
#endif

#define LBAR()                                                                 \
  do {                                                                         \
    asm volatile("s_waitcnt lgkmcnt(0)" ::: "memory");                         \
    __builtin_amdgcn_s_barrier();                                              \
    __builtin_amdgcn_sched_barrier(0);                                         \
  } while (0)

static __device__ __forceinline__ u16 f2bf(float x) {
  unsigned u = __builtin_bit_cast(unsigned, x);
  return (u16)((u + 0x7FFFu + ((u >> 16) & 1u)) >> 16);
}

static __device__ __forceinline__ float2 cmul(float2 a, float2 b) {
  return make_float2(a.x * b.x - a.y * b.y, a.x * b.y + a.y * b.x);
}
static __device__ __forceinline__ float2 cadd(float2 a, float2 b) {
  return make_float2(a.x + b.x, a.y + b.y);
}
static __device__ __forceinline__ float2 conjf2(float2 a) {
  return make_float2(a.x, -a.y);
}
static __device__ __forceinline__ float2 mkC(float a, float b) {
  return make_float2(a, b);
}
static __device__ __forceinline__ float4 pk2(float2 p, float2 q) {
  return make_float4(p.x, p.y, q.x, q.y);
}

static __device__ __forceinline__ float2 twd(int j) {
  float s, c;
  __sincosf((float)j * -0.00613592315154256492f, &s, &c);
  return make_float2(c, s);
}

static __device__ __forceinline__ float gelu_fast(float y) {
  const float t = __builtin_fmaf(0.044715f * y * y, y, y);
  const float e = __expf(-1.5957691216f * t);
  return y * RCP(1.f + e);
}

static __device__ __forceinline__ u32 pack_out(float2 r) {
  const u32 lo = f2bf(gelu_fast(r.x));
  const u32 hi = f2bf(gelu_fast(-r.y));
  return lo | (hi << 16);
}

static __device__ __forceinline__ void gload_lds16(const void* g, void* l) {
  __builtin_amdgcn_global_load_lds(
      (const __attribute__((address_space(1))) u32*)g,
      (__attribute__((address_space(3))) u32*)l, 16, 0, 0);
}

#define BF4(A, B, C, D, Y0, Y1, Y2, Y3)                                        \
  {                                                                            \
    const float apcr = (A).x + (C).x, apci = (A).y + (C).y;                    \
    const float amcr = (A).x - (C).x, amci = (A).y - (C).y;                    \
    const float bpdr = (B).x + (D).x, bpdi = (B).y + (D).y;                    \
    const float bmdr = (B).x - (D).x, bmdi = (B).y - (D).y;                    \
    Y0 = make_float2(apcr + bpdr, apci + bpdi);                                \
    Y2 = make_float2(apcr - bpdr, apci - bpdi);                                \
    Y1 = make_float2(amcr + bmdi, amci - bmdr);                                \
    Y3 = make_float2(amcr - bmdi, amci + bmdr);                                \
  }

// ---------------- K1: merged hope-kernel + filter coeffs (+D folded) + W->bf16
static __device__ __forceinline__ void hope_sum(
    const float* __restrict__ log_dt, const float* __restrict__ Hr,
    const float* __restrict__ Hi, int h, int l, float* outr, float* outi) {
  const float dt = expf(log_dt[h]);
  const float phi = 6.28318530717958647692f * (float)l * (1.0f / 1024.0f);
  float sphi, cphi;
  sincosf(phi, &sphi, &cphi);
  const float nr = (1.f + dt) * cphi + dt - 1.f;
  const float ni = (1.f + dt) * sphi;
  const float dr = (dt - 1.f) * cphi + dt + 1.f;
  const float di = (dt - 1.f) * sphi;
  const float theta = atan2f(ni * dr - nr * di, nr * dr + ni * di);
  float sw, cw;
  sincosf(theta, &sw, &cw);
  const float wr = cw, wi = -sw;  // e^{-i theta}
  float cr = wr, ci = wi;
  float ar = 0.f, ai = 0.f;
  const float* __restrict__ hr = Hr + h * 64;
  const float* __restrict__ hi = Hi + h * 64;
  for (int n = 0; n < 64; ++n) {
    const float a = hr[n], bb = hi[n];
    ar += a * cr - bb * ci;
    ai += a * ci + bb * cr;
    const float t = cr * wr - ci * wi;
    ci = cr * wi + ci * wr;
    cr = t;
  }
  *outr = ar;
  *outi = ai;
}

__global__ __launch_bounds__(512) void build_kep(
    const float* __restrict__ log_dt, const float* __restrict__ Hr,
    const float* __restrict__ Hi, const float* __restrict__ Dv,
    const float* __restrict__ W, float2* __restrict__ kep,
    u16* __restrict__ Wb) {
  __shared__ float2 K1[1024], K2[1024];
  const int c = blockIdx.x;
  const int t = threadIdx.x;
  Wb[c * 1024 + t] = f2bf(W[c * 1024 + t]);
  Wb[c * 1024 + 512 + t] = f2bf(W[c * 1024 + 512 + t]);
  float r, i;
  hope_sum(log_dt, Hr, Hi, c, t, &r, &i);             K1[t] = make_float2(r, i);
  hope_sum(log_dt, Hr, Hi, c, t + 512, &r, &i);       K1[t + 512] = make_float2(r, i);
  hope_sum(log_dt, Hr, Hi, c + 512, t, &r, &i);       K2[t] = make_float2(r, i);
  hope_sum(log_dt, Hr, Hi, c + 512, t + 512, &r, &i); K2[t + 512] = make_float2(r, i);
  __syncthreads();
  const float s = 1.0f / 2048.0f;
  const float dcs = Dv[c] * s;
  for (int q = t; q <= 512; q += 512) {
    float2 kf, kg;
    {
      const int qa = q;
      kf = (qa == 0) ? make_float2(K1[0].x * s, 0.f)
                     : make_float2(0.5f * s * (K1[qa].x + K2[qa - 1].x),
                                   0.5f * s * (K1[qa].y - K2[qa - 1].y));
      const int qb = 1024 - q;
      kg = (qb == 1024) ? make_float2(K2[1023].x * s, 0.f)
           : (qb == 0)  ? make_float2(K1[0].x * s, 0.f)
                        : make_float2(0.5f * s * (K1[qb].x + K2[qb - 1].x),
                                      0.5f * s * (K1[qb].y - K2[qb - 1].y));
    }
    kf.x += dcs;
    kg.x += dcs;
    float2 C1, C2, C3, C4;
    if (q == 0) {
      C1 = make_float2(kf.x + kg.x, kg.y - kf.y);
      C2 = make_float2(-(kg.y + kf.y), kg.x - kf.x);
      C3 = C2;
      C4 = C1;
    } else {
      float st, ct;
      sincosf(3.14159265358979323846f * (float)q * (1.f / 1024.f), &st, &ct);
      const float2 A1 = make_float2(1.f - st, -ct);
      const float2 A2 = make_float2(1.f + st, ct);
      const float2 kgc = make_float2(kg.x, -kg.y);
      const float2 t1 = cmul(kf, A1), t2 = cmul(kgc, A2);
      const float2 t3 = cmul(kf, A2), t4 = cmul(kgc, A1);
      const float2 p1 = make_float2(0.5f * (t1.x + t2.x), 0.5f * (t1.y + t2.y));
      const float2 p2 = make_float2(0.5f * (t3.x + t4.x), 0.5f * (t3.y + t4.y));
      const float2 q1 = make_float2(0.5f * (t1.x - t2.x), 0.5f * (t1.y - t2.y));
      const float2 q2 = make_float2(0.5f * (t3.x - t4.x), 0.5f * (t3.y - t4.y));
      const float2 iWc = make_float2(-st, ct);
      const float2 r1 = cmul(iWc, q1), r2 = cmul(iWc, q2);
      C1 = make_float2(p1.x + r1.x, -(p1.y + r1.y));
      C2 = make_float2(p2.x + r2.x, -(p2.y + r2.y));
      C3 = make_float2(p1.x - r1.x, p1.y - r1.y);
      C4 = make_float2(p2.x - r2.x, p2.y - r2.y);
    }
    float2* o = kep + ((size_t)c * 513 + q) * 4;
    o[0] = C1; o[1] = C2; o[2] = C3; o[3] = C4;
  }
}

// ------- K2: Stockham rfft-conv, 2 rows interleaved per float4 LDS slot -------
static __device__ __forceinline__ void stage_pair(
    const float4* __restrict__ S, float4* __restrict__ D, int t, int sh) {
  const int m = 1 << sh;
  const int kk = t & (m - 1);
  const int o = kk + ((t >> sh) << (sh + 2));
  const float4 va = S[SW(t)];
  const float4 vb = S[SW(t + 256)];
  const float4 vc = S[SW(t + 512)];
  const float4 vd = S[SW(t + 768)];
  const float2 a0 = mkC(va.x, va.y), a1 = mkC(va.z, va.w);
  const float2 b0 = mkC(vb.x, vb.y), b1 = mkC(vb.z, vb.w);
  const float2 c0 = mkC(vc.x, vc.y), c1 = mkC(vc.z, vc.w);
  const float2 d0 = mkC(vd.x, vd.y), d1 = mkC(vd.z, vd.w);
  float2 x0, x1, x2, x3, z0, z1, z2, z3;
  BF4(a0, b0, c0, d0, x0, x1, x2, x3);
  BF4(a1, b1, c1, d1, z0, z1, z2, z3);
  const float2 w1 = twd((t >> sh) << sh);
  const float2 w2 = cmul(w1, w1);
  const float2 w3 = cmul(w2, w1);
  D[SW(o)] = pk2(x0, z0);
  D[SW(o + m)] = pk2(cmul(w1, x1), cmul(w1, z1));
  D[SW(o + 2 * m)] = pk2(cmul(w2, x2), cmul(w2, z2));
  D[SW(o + 3 * m)] = pk2(cmul(w3, x3), cmul(w3, z3));
}

static __device__ __forceinline__ void stage_pair_last(
    const float4* __restrict__ S, float4* __restrict__ D, int t) {
  const float4 va = S[SW(t)];
  const float4 vb = S[SW(t + 256)];
  const float4 vc = S[SW(t + 512)];
  const float4 vd = S[SW(t + 768)];
  const float2 a0 = mkC(va.x, va.y), a1 = mkC(va.z, va.w);
  const float2 b0 = mkC(vb.x, vb.y), b1 = mkC(vb.z, vb.w);
  const float2 c0 = mkC(vc.x, vc.y), c1 = mkC(vc.z, vc.w);
  const float2 d0 = mkC(vd.x, vd.y), d1 = mkC(vd.z, vd.w);
  float2 x0, x1, x2, x3, z0, z1, z2, z3;
  BF4(a0, b0, c0, d0, x0, x1, x2, x3);
  BF4(a1, b1, c1, d1, z0, z1, z2, z3);
  D[SW(t)] = pk2(x0, z0);
  D[SW(t + 256)] = pk2(x1, z1);
  D[SW(t + 512)] = pk2(x2, z2);
  D[SW(t + 768)] = pk2(x3, z3);
}

__global__ __launch_bounds__(256) void fft_conv(
    const float* __restrict__ u, const float2* __restrict__ kep,
    u16* __restrict__ y) {
  __shared__ float4 bufA[1024], bufB[1024];  // 32768 B
  const int bq = blockIdx.x, c = blockIdx.y;
  const int t = threadIdx.x;

  const float4* __restrict__ krow4 = (const float4*)(kep + (size_t)c * (513 * 4));
  const float4 cA0 = krow4[2 * t];
  const float4 cA1 = krow4[2 * (t + 256)];
  const float4 cC  = krow4[2 * (512 - t) + 1];
  const float4 cDq = krow4[2 * (256 - t) + 1];
  const float4 cM  = krow4[1024];

  const int b0 = bq * 2, b1 = bq * 2 + 1;
  const float2* __restrict__ u20 = (const float2*)(u + ((size_t)(b0 * 512 + c)) * 2048);
  const float2* __restrict__ u21 = (const float2*)(u + ((size_t)(b1 * 512 + c)) * 2048);
  u32* __restrict__ yr0 = (u32*)(y + ((size_t)(b0 * 512 + c)) * 2048);
  u32* __restrict__ yr1 = (u32*)(y + ((size_t)(b1 * 512 + c)) * 2048);
  float4* A = bufA;
  float4* B = bufB;

  {
    float2 v0[4], v1[4];
    #pragma unroll
    for (int q = 0; q < 4; ++q) {
      v0[q] = u20[t + 256 * q];
      v1[q] = u21[t + 256 * q];
    }
    float2 x0, x1, x2, x3, z0, z1, z2, z3;
    BF4(v0[0], v0[1], v0[2], v0[3], x0, x1, x2, x3);
    BF4(v1[0], v1[1], v1[2], v1[3], z0, z1, z2, z3);
    const float2 w1 = twd(t);
    const float2 w2 = cmul(w1, w1);
    const float2 w3 = cmul(w2, w1);
    const int o = 4 * t;
    A[SW(o)] = pk2(x0, z0);
    A[SW(o + 1)] = pk2(cmul(w1, x1), cmul(w1, z1));
    A[SW(o + 2)] = pk2(cmul(w2, x2), cmul(w2, z2));
    A[SW(o + 3)] = pk2(cmul(w3, x3), cmul(w3, z3));
  }
  LBAR();
  stage_pair(A, B, t, 2); LBAR();
  stage_pair(B, A, t, 4); LBAR();
  stage_pair(A, B, t, 6); LBAR();
  stage_pair_last(B, A, t); LBAR();

  {
    const int gp0 = (1024 - t) & 1023;
    const float2 w1 = twd(t);
    const float2 w2 = cmul(w1, w1);
    const float2 w3 = cmul(w2, w1);
    const int o = 4 * t;
    const float4 Vf0 = A[SW(t)],       Vg0 = A[SW(gp0)];
    const float4 Vf1 = A[SW(t + 256)], Vg1 = A[SW(768 - t)];
    const float4 Vc  = A[SW(t + 512)], Vcf = A[SW(512 - t)];
    const float4 Vd  = A[SW(t + 768)], Vdf = A[SW(256 - t)];
    const float2 CA1 = mkC(cA0.x, cA0.y), CA2 = mkC(cA0.z, cA0.w);
    const float2 CB1 = mkC(cA1.x, cA1.y), CB2 = mkC(cA1.z, cA1.w);
    const float2 CC3 = mkC(cC.x, cC.y),   CC4 = mkC(cC.z, cC.w);
    const float2 CD3 = mkC(cDq.x, cDq.y), CD4 = mkC(cDq.z, cDq.w);
    const float2 CM1 = mkC(cM.x, cM.y),   CM2 = mkC(cM.z, cM.w);
    float2 Da0, Da1, Db0, Db1, Dc0, Dc1, Dd0, Dd1;
    Da0 = cadd(cmul(CA1, conjf2(mkC(Vf0.x, Vf0.y))), cmul(CA2, mkC(Vg0.x, Vg0.y)));
    Da1 = cadd(cmul(CA1, conjf2(mkC(Vf0.z, Vf0.w))), cmul(CA2, mkC(Vg0.z, Vg0.w)));
    Db0 = cadd(cmul(CB1, conjf2(mkC(Vf1.x, Vf1.y))), cmul(CB2, mkC(Vg1.x, Vg1.y)));
    Db1 = cadd(cmul(CB1, conjf2(mkC(Vf1.z, Vf1.w))), cmul(CB2, mkC(Vg1.z, Vg1.w)));
    if (t == 0) {
      Dc0 = cadd(cmul(CM1, conjf2(mkC(Vc.x, Vc.y))), cmul(CM2, mkC(Vc.x, Vc.y)));
      Dc1 = cadd(cmul(CM1, conjf2(mkC(Vc.z, Vc.w))), cmul(CM2, mkC(Vc.z, Vc.w)));
    } else {
      Dc0 = cadd(cmul(CC3, mkC(Vcf.x, Vcf.y)), cmul(CC4, conjf2(mkC(Vc.x, Vc.y))));
      Dc1 = cadd(cmul(CC3, mkC(Vcf.z, Vcf.w)), cmul(CC4, conjf2(mkC(Vc.z, Vc.w))));
    }
    Dd0 = cadd(cmul(CD3, mkC(Vdf.x, Vdf.y)), cmul(CD4, conjf2(mkC(Vd.x, Vd.y))));
    Dd1 = cadd(cmul(CD3, mkC(Vdf.z, Vdf.w)), cmul(CD4, conjf2(mkC(Vd.z, Vd.w))));
    float2 x0, x1, x2, x3, z0, z1, z2, z3;
    BF4(Da0, Db0, Dc0, Dd0, x0, x1, x2, x3);
    BF4(Da1, Db1, Dc1, Dd1, z0, z1, z2, z3);
    B[SW(o)] = pk2(x0, z0);
    B[SW(o + 1)] = pk2(cmul(w1, x1), cmul(w1, z1));
    B[SW(o + 2)] = pk2(cmul(w2, x2), cmul(w2, z2));
    B[SW(o + 3)] = pk2(cmul(w3, x3), cmul(w3, z3));
  }
  LBAR();

  stage_pair(B, A, t, 2); LBAR();
  stage_pair(A, B, t, 4); LBAR();
  stage_pair(B, A, t, 6); LBAR();
  {
    const float4 va = A[SW(t)];
    const float4 vb = A[SW(t + 256)];
    const float4 vc = A[SW(t + 512)];
    const float4 vd = A[SW(t + 768)];
    const float2 pa0 = mkC(va.x, va.y), pa1 = mkC(va.z, va.w);
    const float2 pb0 = mkC(vb.x, vb.y), pb1 = mkC(vb.z, vb.w);
    const float2 pc0 = mkC(vc.x, vc.y), pc1 = mkC(vc.z, vc.w);
    const float2 pd0 = mkC(vd.x, vd.y), pd1 = mkC(vd.z, vd.w);
    float2 x0, x1, x2, x3, z0, z1, z2, z3;
    BF4(pa0, pb0, pc0, pd0, x0, x1, x2, x3);
    BF4(pa1, pb1, pc1, pd1, z0, z1, z2, z3);
    yr0[t] = pack_out(x0);       yr1[t] = pack_out(z0);
    yr0[t + 256] = pack_out(x1); yr1[t + 256] = pack_out(z1);
    yr0[t + 512] = pack_out(x2); yr1[t + 512] = pack_out(z2);
    yr0[t + 768] = pack_out(x3); yr1[t + 768] = pack_out(z3);
  }
}

// ---------------- K2b: y (B,C,L) bf16 -> yt (B,L,C) bf16 ----------------
__global__ __launch_bounds__(256) void transpose_y(
    const u16* __restrict__ y, u16* __restrict__ yt) {
  __shared__ u16 tile[64][80];
  const int b = blockIdx.z;
  const int tb = blockIdx.x * 64;
  const int cb = blockIdx.y * 64;
  const int tid = threadIdx.x;
  {
    const int tl = (tid & 7) * 8;
    const int cl = tid >> 3;
    #pragma unroll
    for (int h = 0; h < 2; ++h) {
      const int cc = cl + h * 32;
      const u16x8 v = *(const u16x8*)(y + ((size_t)(b * 512 + cb + cc)) * 2048 + tb + tl);
      #pragma unroll
      for (int i = 0; i < 8; ++i) tile[cc][tl + i] = v[i];
    }
  }
  __syncthreads();
  {
    const int c2 = (tid & 7) * 8;
    const int t2 = tid >> 3;
    #pragma unroll
    for (int h = 0; h < 2; ++h) {
      const int tt = t2 + h * 32;
      u16 tmp[8];
      #pragma unroll
      for (int i = 0; i < 8; ++i) tmp[i] = tile[c2 + i][tt];
      *(u16x8*)(yt + ((size_t)(b * 2048 + tb + tt)) * 512 + cb + c2) = *(u16x8*)tmp;
    }
  }
}

// ---------------- K3: 256x256x(K=512) 8-phase GEMM + GLU (R16 version) --------
#define FRAG_A(P, MI, S) __builtin_bit_cast(short8, *(const u16x8*)&lds[       \
    (P) * 16384 + wmh + ((MI) * 16 + lrow) * 64 + ((S) ? cs1 : cs0)])
#define FRAG_B(P, NI, S) __builtin_bit_cast(short8, *(const u16x8*)&lds[       \
    32768 + (P) * 16384 + hBh + (rB + (NI) * 16 + lrow) * 64 + ((S) ? cs1 : cs0)])

#define STAGE_A(KT, H, P) do {                                                 \
    int sr_ = m0 + (H) * 128 + wq8 + l3;                                       \
    int o0_ = (sr_ & 1) ? (512 + (sr_ >> 1)) : (sr_ >> 1);                     \
    gload_lds16(Wb + (size_t)o0_ * 512 + (KT) * 64 + csw,                      \
                lds + (P) * 16384 + (H) * 8192 + wq * 512);                    \
    sr_ += 64;                                                                 \
    int o1_ = (sr_ & 1) ? (512 + (sr_ >> 1)) : (sr_ >> 1);                     \
    gload_lds16(Wb + (size_t)o1_ * 512 + (KT) * 64 + csw,                      \
                lds + (P) * 16384 + (H) * 8192 + 4096 + wq * 512);             \
  } while (0)
#define STAGE_B(KT, H, P) do {                                                 \
    int tr_ = t0b + (H) * 128 + wq8 + l3;                                      \
    gload_lds16(yt + ((size_t)(bb * 2048 + tr_)) * 512 + (KT) * 64 + csw,      \
                lds + 32768 + (P) * 16384 + (H) * 8192 + wq * 512);            \
    gload_lds16(yt + ((size_t)(bb * 2048 + tr_ + 64)) * 512 + (KT) * 64 + csw, \
                lds + 32768 + (P) * 16384 + (H) * 8192 + 4096 + wq * 512);     \
  } while (0)

#define MFMA2(MI, NI, A0, A1)                                                  \
    acc[MI][NI] = __builtin_amdgcn_mfma_f32_16x16x32_bf16(A0, br[NI][0],       \
                                                          acc[MI][NI], 0, 0, 0); \
    acc[MI][NI] = __builtin_amdgcn_mfma_f32_16x16x32_bf16(A1, br[NI][1],       \
                                                          acc[MI][NI], 0, 0, 0);

#define PHASE_CORE(Q, READS, STAGES, VWAIT)                                    \
  {                                                                            \
    short8 a00 = FRAG_A(PP, (Q)*2 + 0, 0), a01 = FRAG_A(PP, (Q)*2 + 0, 1);     \
    short8 a10 = FRAG_A(PP, (Q)*2 + 1, 0), a11 = FRAG_A(PP, (Q)*2 + 1, 1);     \
    READS;                                                                     \
    STAGES;                                                                    \
    __builtin_amdgcn_s_barrier();                                              \
    asm volatile("s_waitcnt lgkmcnt(0)" ::: "memory");                         \
    __builtin_amdgcn_sched_barrier(0);                                         \
    __builtin_amdgcn_s_setprio(1);                                             \
    MFMA2((Q)*2 + 0, 0, a00, a01) MFMA2((Q)*2 + 0, 1, a00, a01)                \
    MFMA2((Q)*2 + 0, 2, a00, a01) MFMA2((Q)*2 + 0, 3, a00, a01)                \
    MFMA2((Q)*2 + 1, 0, a10, a11) MFMA2((Q)*2 + 1, 1, a10, a11)                \
    MFMA2((Q)*2 + 1, 2, a10, a11) MFMA2((Q)*2 + 1, 3, a10, a11)                \
    __builtin_amdgcn_s_setprio(0);                                             \
    __builtin_amdgcn_sched_barrier(0);                                         \
    VWAIT;                                                                     \
    __builtin_amdgcn_s_barrier();                                              \
  }

#define READ_B(P) do {                                                         \
    br[0][0] = FRAG_B(P, 0, 0); br[0][1] = FRAG_B(P, 0, 1);                    \
    br[1][0] = FRAG_B(P, 1, 0); br[1][1] = FRAG_B(P, 1, 1);                    \
    br[2][0] = FRAG_B(P, 2, 0); br[2][1] = FRAG_B(P, 2, 1);                    \
    br[3][0] = FRAG_B(P, 3, 0); br[3][1] = FRAG_B(P, 3, 1);                    \
  } while (0)

__global__ __launch_bounds__(512, 2) void gemm_glu(
    const u16* __restrict__ Wb, const u16* __restrict__ yt,
    const float* __restrict__ bias, float* __restrict__ out) {
  extern __shared__ __align__(16) u16 lds[];
  const int bid = blockIdx.x;
  const int wg = (bid & 7) * 64 + (bid >> 3);  // XCD swizzle (512 = 8*64)
  const int bb = wg >> 5;
  const int mt = (wg >> 3) & 3;
  const int nt = wg & 7;
  const int m0 = mt * 256;
  const int t0b = nt * 256;
  const int tid = threadIdx.x;
  const int lane = tid & 63;
  const int wq = tid >> 6;
  const int wq8 = wq * 8, l3 = lane >> 3;
  const int wm = wq >> 2, wn = wq & 3;
  const int lrow = lane & 15, lq = lane >> 4;
  const int csw = ((lane & 7) ^ l3) * 8;
  const int cs0 = ((lq ^ (lane & 7)) << 3);
  const int cs1 = (((4 + lq) ^ (lane & 7)) << 3);
  const int wmh = wm * 8192;
  const int hBh = (wn >> 1) * 8192;
  const int rB = (wn & 1) * 64;

  f32x4 acc[8][4];
  const f32x4 z4 = {0.f, 0.f, 0.f, 0.f};
  #pragma unroll
  for (int mi = 0; mi < 8; ++mi)
    #pragma unroll
    for (int ni = 0; ni < 4; ++ni) acc[mi][ni] = z4;
  short8 br[4][2];

  STAGE_A(0, 0, 0); STAGE_A(0, 1, 0);
  STAGE_B(0, 0, 0); STAGE_B(0, 1, 0);
  STAGE_B(1, 0, 1); STAGE_B(1, 1, 1);
  asm volatile("s_waitcnt vmcnt(4)" ::: "memory");
  __builtin_amdgcn_s_barrier();

  #pragma unroll
  for (int j = 0; j < 4; ++j) {
    const int e2 = 2 * j + 2, o1 = 2 * j + 1, o3 = 2 * j + 3;
    #define PP 0
    PHASE_CORE(0, READ_B(0), STAGE_A(o1, 0, 1), )
    PHASE_CORE(1, , { STAGE_A(o1, 1, 1); if (j < 3) STAGE_B(e2, 0, 0); }, )
    PHASE_CORE(2, , if (j < 3) STAGE_B(e2, 1, 0), )
    PHASE_CORE(3, , ,
               if (j < 3) { asm volatile("s_waitcnt vmcnt(4)" ::: "memory"); }
               else { asm volatile("s_waitcnt vmcnt(0)" ::: "memory"); })
    #undef PP
    #define PP 1
    PHASE_CORE(0, READ_B(1), if (j < 3) STAGE_A(e2, 0, 0), )
    PHASE_CORE(1, , if (j < 3) STAGE_A(e2, 1, 0), )
    PHASE_CORE(2, , if (j < 3) STAGE_B(o3, 0, 1), )
    PHASE_CORE(3, , if (j < 3) STAGE_B(o3, 1, 1),
               if (j < 3) { asm volatile("s_waitcnt vmcnt(4)" ::: "memory"); })
    #undef PP
  }

  #pragma unroll
  for (int mi = 0; mi < 8; ++mi) {
    const int sr0 = m0 + wm * 128 + mi * 16 + lq * 4;
    const int ch = sr0 >> 1;
    const float ba0 = bias[ch],     bg0 = bias[512 + ch];
    const float ba1 = bias[ch + 1], bg1 = bias[512 + ch + 1];
    #pragma unroll
    for (int ni = 0; ni < 4; ++ni) {
      const int t = t0b + wn * 64 + ni * 16 + (lane & 15);
      const f32x4 v = acc[mi][ni];
      const float a0 = v[0] + ba0, g0 = v[1] + bg0;
      const float a1 = v[2] + ba1, g1 = v[3] + bg1;
      out[((size_t)(bb * 512 + ch)) * 2048 + t]     = a0 * RCP(1.f + __expf(-g0));
      out[((size_t)(bb * 512 + ch + 1)) * 2048 + t] = a1 * RCP(1.f + __expf(-g1));
    }
  }
}

extern "C" void kernel_launch(void* const* d_in, const int* in_sizes, int n_in,
                              void* d_out, int out_size, void* d_ws, size_t ws_size,
                              hipStream_t stream) {
  (void)in_sizes; (void)n_in; (void)out_size; (void)ws_size;
  const float* u      = (const float*)d_in[0];
  const float* log_dt = (const float*)d_in[1];
  const float* Hr     = (const float*)d_in[2];
  const float* Hi     = (const float*)d_in[3];
  const float* Dv     = (const float*)d_in[4];
  const float* W      = (const float*)d_in[5];
  const float* bias   = (const float*)d_in[6];

  char* ws = (char*)d_ws;
  float2* kep = (float2*)(ws);                     // 8.4 MB
  u16*    Wb  = (u16*)  (ws + ((size_t)9 << 20));  // 1 MB
  u16*    yt  = (u16*)  (ws + ((size_t)12 << 20)); // 32 MB
  u16*    ybf = (u16*)d_out;                       // bf16 y staged in d_out

  build_kep<<<dim3(512), 512, 0, stream>>>(log_dt, Hr, Hi, Dv, W, kep, Wb);
  fft_conv<<<dim3(8, 512), 256, 0, stream>>>(u, kep, ybf);
  transpose_y<<<dim3(32, 8, 16), 256, 0, stream>>>(ybf, yt);
  gemm_glu<<<dim3(512), 512, 131072, stream>>>(Wb, yt, bias, (float*)d_out);
}